// Round 1
// baseline (406.410 us; speedup 1.0000x reference)
//
#include <hip/hip_runtime.h>
#include <math.h>

#define KDIM 32
#define MDIM 256
#define NDIM 2048
#define NNLS_TOL 1e-6f
#define LDPAD 33  // pad leading dim to break 32-bank conflicts

// ---------------- AtA = A^T A  (32x32) ----------------
__global__ __launch_bounds__(1024) void ata_kernel(const float* __restrict__ A,
                                                   float* __restrict__ AtA) {
  __shared__ float As[MDIM * KDIM];  // 32 KB
  const int t = threadIdx.x;
  for (int i = t; i < MDIM * KDIM; i += 1024) As[i] = A[i];
  __syncthreads();
  const int i = t >> 5, j = t & 31;
  float acc = 0.f;
#pragma unroll 8
  for (int m = 0; m < MDIM; ++m) acc += As[m * KDIM + i] * As[m * KDIM + j];
  AtA[i * KDIM + j] = acc;
}

// ---------------- AtX = A^T X  (32x2048) ----------------
__global__ __launch_bounds__(256) void atx_kernel(const float* __restrict__ A,
                                                  const float* __restrict__ X,
                                                  float* __restrict__ AtX) {
  __shared__ float As[MDIM * KDIM];
  const int t = threadIdx.x;
  for (int i = t; i < MDIM * KDIM; i += 256) As[i] = A[i];
  __syncthreads();
  const int n = blockIdx.x * 256 + t;
  float acc[KDIM];
#pragma unroll
  for (int k = 0; k < KDIM; ++k) acc[k] = 0.f;
  for (int m = 0; m < MDIM; ++m) {
    const float x = X[m * NDIM + n];  // coalesced across n
#pragma unroll
    for (int k = 0; k < KDIM; ++k) acc[k] += As[m * KDIM + k] * x;  // LDS broadcast
  }
#pragma unroll
  for (int k = 0; k < KDIM; ++k) AtX[k * NDIM + n] = acc[k];
}

// ---------------- per-column fnnls: one wave per column ----------------
__global__ __launch_bounds__(64) void nnls_kernel(const float* __restrict__ AtA_g,
                                                  const float* __restrict__ AtX,
                                                  float* __restrict__ S) {
  __shared__ float AtA_s[KDIM * LDPAD];  // padded copy of AtA
  __shared__ float M[KDIM * LDPAD];      // compacted active-set system
  __shared__ float rhs[KDIM];
  __shared__ float xs[KDIM];
  __shared__ float atb[KDIM];
  __shared__ float s_sh[KDIM];
  __shared__ float z_sh[KDIM];
  __shared__ int   idx[KDIM];

  const int l = threadIdx.x;   // 0..63; lanes 0..31 own coefficients
  const int n = blockIdx.x;    // column

  // stage AtA (padded) and load Atb
  for (int i = l; i < KDIM * KDIM; i += 64) {
    const int r = i >> 5, c = i & 31;
    AtA_s[r * LDPAD + c] = AtA_g[i];
  }
  if (l < KDIM) {
    atb[l] = AtX[l * NDIM + n];
    s_sh[l] = 0.f;
    z_sh[l] = 0.f;
  }
  __syncthreads();

  unsigned int P = 0u;  // active-set bitmask (wave-uniform)

  // masked solve on compacted active set -> z_sh (zeros elsewhere)
  auto solve = [&](unsigned int Pm) {
    const int p = __popc(Pm);
    if (p == 0) {
      if (l < KDIM) z_sh[l] = 0.f;
      __syncthreads();
      return;
    }
    const bool act = (l < KDIM) && ((Pm >> l) & 1u);
    const int rk = (l < KDIM) ? __popc(Pm & ((1u << l) - 1u)) : 0;
    if (act) idx[rk] = l;
    __syncthreads();
    // build compact M (p x p) and rhs
    if (l < p) {
      const int gi = idx[l];
      for (int c = 0; c < p; ++c) M[l * LDPAD + c] = AtA_s[gi * LDPAD + idx[c]];
      rhs[l] = atb[gi];
    }
    __syncthreads();
    // forward elimination (SPD, no pivoting needed)
    for (int j = 0; j < p - 1; ++j) {
      if (l > j && l < p) {
        const float f = M[l * LDPAD + j] / M[j * LDPAD + j];
        for (int c = j + 1; c < p; ++c) M[l * LDPAD + c] -= f * M[j * LDPAD + c];
        rhs[l] -= f * rhs[j];
      }
      __syncthreads();
    }
    // back substitution
    for (int j = p - 1; j >= 0; --j) {
      const float xj = rhs[j] / M[j * LDPAD + j];  // broadcast reads, uniform value
      if (l == 0) xs[j] = xj;
      if (l < j) rhs[l] -= M[l * LDPAD + j] * xj;
      __syncthreads();
    }
    // scatter back
    if (l < KDIM) z_sh[l] = act ? xs[rk] : 0.f;
    __syncthreads();
  };

  for (int it_out = 0; it_out < 96; ++it_out) {
    // w = Atb - AtA @ s (s is zero on inactive, so full sum is fine)
    float w = 0.f;
    if (l < KDIM) {
      float acc = atb[l];
      for (int j = 0; j < KDIM; ++j) acc -= AtA_s[l * LDPAD + j] * s_sh[j];
      w = acc;
    }
    const bool inact = (l < KDIM) && !((P >> l) & 1u);
    float wv = inact ? w : -INFINITY;
    int wi = inact ? l : KDIM;
    // argmax reduce, tie-break lowest index (jnp.argmax semantics)
    for (int off = 32; off >= 1; off >>= 1) {
      const float ow = __shfl_xor(wv, off);
      const int oi = __shfl_xor(wi, off);
      if (ow > wv || (ow == wv && oi < wi)) { wv = ow; wi = oi; }
    }
    if (!(wv > NNLS_TOL)) break;  // uniform
    P |= (1u << wi);
    solve(P);

    // inner loop: remove variables driven nonpositive
    for (int it_in = 0; it_in < 96; ++it_in) {
      const bool act = (l < KDIM) && ((P >> l) & 1u);
      const float z = (l < KDIM) ? z_sh[l] : 0.f;
      const bool msk = act && (z <= NNLS_TOL);
      const unsigned long long bal = __ballot(msk);
      if (bal == 0ull) break;  // uniform
      const float sv = (l < KDIM) ? s_sh[l] : 0.f;
      const float denom = sv - z;
      float ratio = msk ? (sv / ((denom != 0.f) ? denom : 1.f)) : INFINITY;
      for (int off = 32; off >= 1; off >>= 1) ratio = fminf(ratio, __shfl_xor(ratio, off));
      const float alpha = ratio;
      float snew = sv + alpha * (z - sv);
      const bool keep = act && (snew > NNLS_TOL);
      const unsigned long long kb = __ballot(keep);
      P = (unsigned int)(kb & 0xffffffffull);
      snew = keep ? snew : 0.f;
      if (l < KDIM) s_sh[l] = snew;
      __syncthreads();
      solve(P);
    }

    // s = where(P, z, 0)
    if (l < KDIM) s_sh[l] = ((P >> l) & 1u) ? z_sh[l] : 0.f;
    __syncthreads();
  }

  if (l < KDIM) S[l * NDIM + n] = s_sh[l];
}

extern "C" void kernel_launch(void* const* d_in, const int* in_sizes, int n_in,
                              void* d_out, int out_size, void* d_ws, size_t ws_size,
                              hipStream_t stream) {
  const float* X = (const float*)d_in[0];  // [256, 2048]
  const float* A = (const float*)d_in[1];  // [256, 32]
  float* S = (float*)d_out;                // [32, 2048]
  float* AtA = (float*)d_ws;               // 1024 floats
  float* AtX = AtA + KDIM * KDIM;          // 65536 floats

  ata_kernel<<<1, 1024, 0, stream>>>(A, AtA);
  atx_kernel<<<NDIM / 256, 256, 0, stream>>>(A, X, AtX);
  nnls_kernel<<<NDIM, 64, 0, stream>>>(AtA, AtX, S);
}

// Round 2
// 206.424 us; speedup vs baseline: 1.9688x; 1.9688x over previous
//
#include <hip/hip_runtime.h>
#include <math.h>

#define KDIM 32
#define MDIM 256
#define NDIM 2048
#define NNLS_TOL 1e-6f

// ---------------- helpers ----------------
__device__ __forceinline__ float lane_bcast(float x, int lane) {
  // compile-time lane -> v_readlane_b32 (SGPR broadcast), no LDS, no bpermute
  return __int_as_float(__builtin_amdgcn_readlane(__float_as_int(x), lane));
}
__device__ __forceinline__ float fast_rcp(float x) {
  float r;
  asm("v_rcp_f32 %0, %1" : "=v"(r) : "v"(x));
  r = r * (2.0f - x * r);  // one Newton step -> ~1 ulp
  return r;
}

// ---------------- AtA = A^T A  (32x32) ----------------
__global__ __launch_bounds__(1024) void ata_kernel(const float* __restrict__ A,
                                                   float* __restrict__ AtA) {
  __shared__ float As[MDIM * KDIM];  // 32 KB
  const int t = threadIdx.x;
  for (int i = t; i < MDIM * KDIM; i += 1024) As[i] = A[i];
  __syncthreads();
  const int i = t >> 5, j = t & 31;
  float acc = 0.f;
#pragma unroll 8
  for (int m = 0; m < MDIM; ++m) acc += As[m * KDIM + i] * As[m * KDIM + j];
  AtA[i * KDIM + j] = acc;
}

// ---------------- AtX = A^T X  (32x2048) ----------------
__global__ __launch_bounds__(256) void atx_kernel(const float* __restrict__ A,
                                                  const float* __restrict__ X,
                                                  float* __restrict__ AtX) {
  __shared__ float As[MDIM * KDIM];
  const int t = threadIdx.x;
  for (int i = t; i < MDIM * KDIM; i += 256) As[i] = A[i];
  __syncthreads();
  const int n = blockIdx.x * 256 + t;
  float acc[KDIM];
#pragma unroll
  for (int k = 0; k < KDIM; ++k) acc[k] = 0.f;
  for (int m = 0; m < MDIM; ++m) {
    const float x = X[m * NDIM + n];  // coalesced across n
#pragma unroll
    for (int k = 0; k < KDIM; ++k) acc[k] += As[m * KDIM + k] * x;  // LDS broadcast
  }
#pragma unroll
  for (int k = 0; k < KDIM; ++k) AtX[k * NDIM + n] = acc[k];
}

// ---------------- per-column fnnls: one wave per column, all-register solver ---
// Lane l owns row r = l&31 of AtA and of the masked system M (32 statically
// indexed VGPRs each). Hi half (lanes 32-63) mirrors lo half so every branch
// condition is uniform across the full wave. Active set P lives in an SGPR
// bitmask; inactive elimination steps are skipped with scalar branches.
// No LDS, no __syncthreads anywhere in the solver.
__global__ __launch_bounds__(64) void nnls_kernel(const float* __restrict__ AtA_g,
                                                  const float* __restrict__ AtX,
                                                  float* __restrict__ S) {
  const int l = threadIdx.x;
  const int r = l & 31;
  const int n = blockIdx.x;

  float ata[KDIM];
#pragma unroll
  for (int q = 0; q < KDIM / 4; ++q) {
    const float4 v = reinterpret_cast<const float4*>(AtA_g + r * KDIM)[q];
    ata[4 * q + 0] = v.x;
    ata[4 * q + 1] = v.y;
    ata[4 * q + 2] = v.z;
    ata[4 * q + 3] = v.w;
  }
  const float atb = AtX[r * NDIM + n];

  float sv = 0.f;   // s[r]
  float z = 0.f;    // z[r]
  unsigned int P = 0u;
  int it_out = 0, it_in = 0;
  bool pick = true;

  while (true) {
    bool actl_pre;
    if (pick) {
      // outer: w = Atb - AtA @ s; pick argmax over inactive; break if none > TOL
      if (it_out >= 96) break;
      float w = atb;
#pragma unroll
      for (int c = 0; c < KDIM; ++c) w = fmaf(-ata[c], lane_bcast(sv, c), w);
      const bool inact = !((P >> r) & 1u);
      float wv = inact ? w : -INFINITY;
      int wi = inact ? r : KDIM;
#pragma unroll
      for (int off = 16; off >= 1; off >>= 1) {
        const float ow = __shfl_xor(wv, off);
        const int oi = __shfl_xor(wi, off);
        if (ow > wv || (ow == wv && oi < wi)) { wv = ow; wi = oi; }  // first-max
      }
      if (!(wv > NNLS_TOL)) break;  // uniform (hi half mirrors)
      const int j = __builtin_amdgcn_readfirstlane(wi);
      P |= (1u << j);
      ++it_out;
      it_in = 0;
    } else {
      // inner alpha step (reference semantics exactly)
      const bool act = (P >> r) & 1u;
      const bool msk = act && (z <= NNLS_TOL);
      const float denom = sv - z;
      float ratio = msk ? (sv / ((denom != 0.f) ? denom : 1.f)) : INFINITY;
#pragma unroll
      for (int off = 16; off >= 1; off >>= 1) ratio = fminf(ratio, __shfl_xor(ratio, off));
      const float snew = fmaf(ratio, z - sv, sv);  // s + alpha*(z-s)
      const bool keep = act && (snew > NNLS_TOL);
      const unsigned long long kb = __ballot(keep);
      P = (unsigned int)(kb & 0xffffffffull);
      sv = keep ? snew : 0.f;
      ++it_in;
    }

    // ---- masked solve: (AtA o PP^T + diag(1-P)) z = P o Atb, in registers ----
    actl_pre = (P >> r) & 1u;
    float m[KDIM];
#pragma unroll
    for (int c = 0; c < KDIM; ++c) {
      const bool actc = (P >> c) & 1u;  // scalar bit test
      m[c] = (actl_pre && actc) ? ata[c] : ((r == c) ? 1.f : 0.f);
    }
    float rhs = actl_pre ? atb : 0.f;
    // forward elimination (SPD, no pivoting); skip inactive j (no-op rows)
#pragma unroll
    for (int j = 0; j < KDIM - 1; ++j) {
      if ((P >> j) & 1u) {
        const float piv = lane_bcast(m[j], j);
        const float inv = fast_rcp(piv);
        const float f = (r > j) ? m[j] * inv : 0.f;
#pragma unroll
        for (int c = j + 1; c < KDIM; ++c) m[c] = fmaf(-f, lane_bcast(m[c], j), m[c]);
        rhs = fmaf(-f, lane_bcast(rhs, j), rhs);
      }
    }
    // back substitution
    z = 0.f;
#pragma unroll
    for (int j = KDIM - 1; j >= 0; --j) {
      if ((P >> j) & 1u) {
        const float diag = lane_bcast(m[j], j);
        const float rj = lane_bcast(rhs, j);
        const float xj = rj * fast_rcp(diag);
        if (r == j) z = xj;
        if (r < j) rhs = fmaf(-m[j], xj, rhs);
      }
    }

    // inner-loop condition: any(P & z<=TOL) && it_in < 96
    const bool bad = ((P >> r) & 1u) && (z <= NNLS_TOL);
    const unsigned long long bb = __ballot(bad);
    if ((bb & 0xffffffffull) != 0ull && it_in < 96) {
      pick = false;
    } else {
      sv = actl_pre ? z : 0.f;  // s = where(P, z, 0)
      pick = true;
    }
  }

  if (l < KDIM) S[r * NDIM + n] = sv;
}

extern "C" void kernel_launch(void* const* d_in, const int* in_sizes, int n_in,
                              void* d_out, int out_size, void* d_ws, size_t ws_size,
                              hipStream_t stream) {
  const float* X = (const float*)d_in[0];  // [256, 2048]
  const float* A = (const float*)d_in[1];  // [256, 32]
  float* S = (float*)d_out;                // [32, 2048]
  float* AtA = (float*)d_ws;               // 1024 floats
  float* AtX = AtA + KDIM * KDIM;          // 65536 floats

  ata_kernel<<<1, 1024, 0, stream>>>(A, AtA);
  atx_kernel<<<NDIM / 256, 256, 0, stream>>>(A, X, AtX);
  nnls_kernel<<<NDIM, 64, 0, stream>>>(AtA, AtX, S);
}

// Round 3
// 68.283 us; speedup vs baseline: 5.9519x; 3.0231x over previous
//
#include <hip/hip_runtime.h>
#include <math.h>

#define KDIM 32
#define MDIM 256
#define NDIM 2048
#define NNLS_TOL 1e-6f

// ---------------- helpers ----------------
__device__ __forceinline__ float lane_bcast(float x, int lane) {
  // compile-time lane -> v_readlane_b32 (SGPR broadcast), no LDS, no bpermute
  return __int_as_float(__builtin_amdgcn_readlane(__float_as_int(x), lane));
}
__device__ __forceinline__ float fast_rcp(float x) {
  float r;
  asm("v_rcp_f32 %0, %1" : "=v"(r) : "v"(x));
  r = r * (2.0f - x * r);  // one Newton step; protects the 3e-3 margin
  return r;
}

// ---------------- AtA = A^T A (32x32), plus its packed LU factor ----------------
// The unconstrained (all-active) solve is shared by every column: factor once here.
__global__ __launch_bounds__(256) void ata_kernel(const float* __restrict__ A,
                                                  float* __restrict__ AtA,
                                                  float* __restrict__ LU) {
  __shared__ float As[MDIM * KDIM];    // 32 KB
  __shared__ float AtAs[KDIM * KDIM];  // 4 KB
  const int t = threadIdx.x;
  for (int i = t; i < MDIM * KDIM; i += 256) As[i] = A[i];
  __syncthreads();
  {
    const int i = t >> 3;          // row 0..31
    const int j0 = (t & 7) * 4;    // col group
    float a0 = 0.f, a1 = 0.f, a2 = 0.f, a3 = 0.f;
    for (int m = 0; m < MDIM; ++m) {
      const float ai = As[m * KDIM + i];
      const float4 vj = *reinterpret_cast<const float4*>(&As[m * KDIM + j0]);
      a0 = fmaf(ai, vj.x, a0);
      a1 = fmaf(ai, vj.y, a1);
      a2 = fmaf(ai, vj.z, a2);
      a3 = fmaf(ai, vj.w, a3);
    }
    AtAs[i * KDIM + j0 + 0] = a0; AtA[i * KDIM + j0 + 0] = a0;
    AtAs[i * KDIM + j0 + 1] = a1; AtA[i * KDIM + j0 + 1] = a1;
    AtAs[i * KDIM + j0 + 2] = a2; AtA[i * KDIM + j0 + 2] = a2;
    AtAs[i * KDIM + j0 + 3] = a3; AtA[i * KDIM + j0 + 3] = a3;
  }
  __syncthreads();
  // one wave: dense register GE, store L multipliers below diag, U on/above
  if (t < 64) {
    const int r = t & 31;
    float m[KDIM];
#pragma unroll
    for (int c = 0; c < KDIM; ++c) m[c] = AtAs[r * KDIM + c];
#pragma unroll
    for (int j = 0; j < KDIM - 1; ++j) {
      const float inv = fast_rcp(lane_bcast(m[j], j));
      const float f = (r > j) ? m[j] * inv : 0.f;
#pragma unroll
      for (int c = j + 1; c < KDIM; ++c) m[c] = fmaf(-f, lane_bcast(m[c], j), m[c]);
      if (r > j) m[j] = f;  // pack multiplier
    }
    if (t < 32) {
#pragma unroll
      for (int c = 0; c < KDIM; ++c) LU[r * KDIM + c] = m[c];
    }
  }
}

// ---------------- AtX = A^T X (32x2048) ----------------
__global__ __launch_bounds__(256) void atx_kernel(const float* __restrict__ A,
                                                  const float* __restrict__ X,
                                                  float* __restrict__ AtX) {
  __shared__ float As[MDIM * KDIM];
  const int t = threadIdx.x;
  for (int i = t; i < MDIM * KDIM; i += 256) As[i] = A[i];
  __syncthreads();
  const int n = blockIdx.x * 256 + t;
  float acc[KDIM];
#pragma unroll
  for (int k = 0; k < KDIM; ++k) acc[k] = 0.f;
  for (int m = 0; m < MDIM; ++m) {
    const float x = X[m * NDIM + n];
#pragma unroll
    for (int k = 0; k < KDIM; ++k) acc[k] = fmaf(As[m * KDIM + k], x, acc[k]);
  }
#pragma unroll
  for (int k = 0; k < KDIM; ++k) AtX[k * NDIM + n] = acc[k];
}

// ---------------- per-column NNLS: block principal pivoting, all-register ------
// Lane l owns row r=l&31; hi half mirrors lo so all branches are wave-uniform.
// KKT fixed point is unique (AtA SPD) => matches the reference's active-set
// solution within solver tolerance regardless of pivot order.
__global__ __launch_bounds__(64) void nnls_kernel(const float* __restrict__ AtA_g,
                                                  const float* __restrict__ LU_g,
                                                  const float* __restrict__ AtX,
                                                  float* __restrict__ S) {
  const int l = threadIdx.x;
  const int r = l & 31;
  const int n = blockIdx.x;

  float ata[KDIM], lu[KDIM];
#pragma unroll
  for (int q = 0; q < KDIM / 4; ++q) {
    const float4 v = reinterpret_cast<const float4*>(AtA_g + r * KDIM)[q];
    ata[4 * q + 0] = v.x; ata[4 * q + 1] = v.y; ata[4 * q + 2] = v.z; ata[4 * q + 3] = v.w;
    const float4 u = reinterpret_cast<const float4*>(LU_g + r * KDIM)[q];
    lu[4 * q + 0] = u.x; lu[4 * q + 1] = u.y; lu[4 * q + 2] = u.z; lu[4 * q + 3] = u.w;
  }
  const float atb = AtX[r * NDIM + n];

  // masked solve: (AtA o PP^T + diag(1-P)) z = P o Atb, registers + readlane only
  auto solve = [&](unsigned int Pm) -> float {
    const bool actl = (Pm >> r) & 1u;
    float m[KDIM];
#pragma unroll
    for (int c = 0; c < KDIM; ++c) {
      const bool actc = (Pm >> c) & 1u;
      m[c] = (actl && actc) ? ata[c] : ((r == c) ? 1.f : 0.f);
    }
    float rhs = actl ? atb : 0.f;
#pragma unroll
    for (int j = 0; j < KDIM - 1; ++j) {
      if ((Pm >> j) & 1u) {
        const float inv = fast_rcp(lane_bcast(m[j], j));
        const float f = (r > j) ? m[j] * inv : 0.f;
#pragma unroll
        for (int c = j + 1; c < KDIM; ++c) m[c] = fmaf(-f, lane_bcast(m[c], j), m[c]);
        rhs = fmaf(-f, lane_bcast(rhs, j), rhs);
      }
    }
    float zz = 0.f;
#pragma unroll
    for (int j = KDIM - 1; j >= 0; --j) {
      if ((Pm >> j) & 1u) {
        const float xj = lane_bcast(rhs, j) * fast_rcp(lane_bcast(m[j], j));
        if (r == j) zz = xj;
        if (r < j) rhs = fmaf(-m[j], xj, rhs);
      }
    }
    return zz;
  };

  unsigned int P;
  float z;
  {
    const unsigned long long b0 = __ballot(atb > NNLS_TOL);
    const unsigned int P0 = (unsigned int)(b0 & 0xffffffffull);
    if (P0 == 0xffffffffu) {
      // shared-LU fast path: forward/back substitution only (~260 VALU)
      P = P0;
      float rhs = atb;
#pragma unroll
      for (int j = 0; j < KDIM - 1; ++j) {
        const float fj = (r > j) ? lu[j] : 0.f;
        rhs = fmaf(-fj, lane_bcast(rhs, j), rhs);
      }
      z = 0.f;
#pragma unroll
      for (int j = KDIM - 1; j >= 0; --j) {
        const float xj = lane_bcast(rhs, j) * fast_rcp(lane_bcast(lu[j], j));
        if (r == j) z = xj;
        const float uj = (r < j) ? lu[j] : 0.f;
        rhs = fmaf(-uj, xj, rhs);
      }
    } else {
      // rare/robustness path: let the loop's block step add P0 and solve
      P = 0u;
      z = 0.f;
    }
  }

  // block principal pivoting with Murty least-index safeguard
  int ninf_best = 1000, budget = 3;
  for (int it = 0; it < 100; ++it) {
    const bool act = (P >> r) & 1u;
    const float zm = act ? z : 0.f;
    float w = atb;
#pragma unroll
    for (int c = 0; c < KDIM; ++c) w = fmaf(-ata[c], lane_bcast(zm, c), w);
    const unsigned long long bb = __ballot(act && (z <= NNLS_TOL));
    const unsigned long long vb = __ballot((!act) && (w > NNLS_TOL));
    const unsigned int bad = (unsigned int)(bb & 0xffffffffull);
    const unsigned int viol = (unsigned int)(vb & 0xffffffffull);
    const unsigned int u = bad | viol;
    if (u == 0u) break;  // KKT satisfied (uniform)
    const int ninf = __popc(u);
    bool useblock;
    if (ninf < ninf_best) { ninf_best = ninf; budget = 3; useblock = true; }
    else if (budget > 0) { --budget; useblock = true; }
    else { useblock = false; }
    if (useblock) {
      P = (P & ~bad) | viol;
    } else {
      const int j = __ffs(u) - 1;  // Murty: least-index single flip (finite for SPD)
      P ^= (1u << j);
    }
    z = solve(P);
  }

  if (l < KDIM) S[r * NDIM + n] = ((P >> r) & 1u) ? z : 0.f;
}

extern "C" void kernel_launch(void* const* d_in, const int* in_sizes, int n_in,
                              void* d_out, int out_size, void* d_ws, size_t ws_size,
                              hipStream_t stream) {
  const float* X = (const float*)d_in[0];  // [256, 2048]
  const float* A = (const float*)d_in[1];  // [256, 32]
  float* S = (float*)d_out;                // [32, 2048]
  float* AtA = (float*)d_ws;               // 1024 floats
  float* LU = AtA + KDIM * KDIM;           // 1024 floats
  float* AtX = LU + KDIM * KDIM;           // 65536 floats

  ata_kernel<<<1, 256, 0, stream>>>(A, AtA, LU);
  atx_kernel<<<NDIM / 256, 256, 0, stream>>>(A, X, AtX);
  nnls_kernel<<<NDIM, 64, 0, stream>>>(AtA, LU, AtX, S);
}